// Round 14
// baseline (430.886 us; speedup 1.0000x reference)
//
#include <hip/hip_runtime.h>
#include <hip/hip_bf16.h>

typedef __attribute__((ext_vector_type(8))) short bf16x8;
typedef __attribute__((ext_vector_type(4))) float f32x4;

#define NB   256
#define TT   512
#define DDEC 512
#define DENC 1024
#define DATT 128
#define NF   32
#define KW   31
#define PW   15

#define GLDS16(g, l)                                                        \
  __builtin_amdgcn_global_load_lds(                                         \
      (const __attribute__((address_space(1))) void*)(uintptr_t)(g),        \
      (__attribute__((address_space(3))) void*)(uintptr_t)(l), 16, 0, 0)

__device__ __forceinline__ float fast_tanh(float x) {
  float e = __expf(2.f * x);
  return 1.f - 2.f / (e + 1.f);
}

// ---------- prep: WkT[a][k] = bf16(Wk[k][a]) ----------
__global__ __launch_bounds__(256) void prep_wkt(const float* __restrict__ Wk,
                                                __hip_bfloat16* __restrict__ WkT) {
  int idx = blockIdx.x * 256 + threadIdx.x;
  int k2 = idx >> 7, a = idx & 127;
  int k = k2 * 2;
  union { ushort2 u; __hip_bfloat16 h[2]; } cv;
  cv.h[0] = __float2bfloat16(Wk[(size_t)k * DATT + a]);
  cv.h[1] = __float2bfloat16(Wk[(size_t)(k + 1) * DATT + a]);
  *reinterpret_cast<ushort2*>(WkT + (size_t)a * 1024 + k) = cv.u;
}

// ---------- prep: wlocT[a][f] = bf16(Wloc[f][a]) ----------
__global__ __launch_bounds__(256) void prep_wloc(const float* __restrict__ Wloc,
                                                 __hip_bfloat16* __restrict__ wlocT) {
  int idx = blockIdx.x * 256 + threadIdx.x;
  int a = idx >> 5, f = idx & 31;
  wlocT[idx] = __float2bfloat16(Wloc[(size_t)f * DATT + a]);
}

// ---------- prep: qv[b][a] = query[b,:] @ Wq[:,a] ----------
__global__ __launch_bounds__(128) void prep_qv(const float* __restrict__ query,
                                               const float* __restrict__ Wq,
                                               float* __restrict__ qvg) {
  __shared__ float qr[DDEC];
  const int b = blockIdx.x, tid = threadIdx.x;
  for (int i = tid; i < DDEC; i += 128) qr[i] = query[(size_t)b * DDEC + i];
  __syncthreads();
  float a0 = 0.f, a1 = 0.f, a2 = 0.f, a3 = 0.f;
#pragma unroll 4
  for (int d = 0; d < DDEC; d += 4) {
    a0 = fmaf(qr[d + 0], Wq[(size_t)(d + 0) * DATT + tid], a0);
    a1 = fmaf(qr[d + 1], Wq[(size_t)(d + 1) * DATT + tid], a1);
    a2 = fmaf(qr[d + 2], Wq[(size_t)(d + 2) * DATT + tid], a2);
    a3 = fmaf(qr[d + 3], Wq[(size_t)(d + 3) * DATT + tid], a3);
  }
  qvg[(size_t)b * DATT + tid] = (a0 + a1) + (a2 + a3);
}

// ---------- prep: locf[b][t][f] = bf16(conv1d(attw)[f][t]) ----------
__global__ __launch_bounds__(512) void prep_locf(const float* __restrict__ attwg,
                                                 const float* __restrict__ convw,
                                                 const float* __restrict__ convb,
                                                 __hip_bfloat16* __restrict__ locf) {
  __shared__ float at[TT + 2 * PW];
  __shared__ float cw[NF][KW];
  __shared__ float cb[NF];
  const int b = blockIdx.x, t = threadIdx.x;
  for (int i = t; i < TT + 2 * PW; i += 512) {
    int g = i - PW;
    at[i] = (g >= 0 && g < TT) ? attwg[(size_t)b * TT + g] : 0.f;
  }
  for (int i = t; i < NF * KW; i += 512) cw[i / KW][i % KW] = convw[i];
  if (t < NF) cb[t] = convb[t];
  __syncthreads();
  union { __hip_bfloat16 h[NF]; ushort4 u4[8]; } o;
#pragma unroll
  for (int f = 0; f < NF; ++f) {
    float a = cb[f];
#pragma unroll
    for (int k = 0; k < KW; ++k) a = fmaf(cw[f][k], at[t + k], a);
    o.h[f] = __float2bfloat16(a);
  }
  ushort4* dst = reinterpret_cast<ushort4*>(locf + ((size_t)b * TT + t) * NF);
#pragma unroll
  for (int i = 0; i < 8; ++i) dst[i] = o.u4[i];
}

// ---------- epass: DMA-staged A + reg B, FIFO-correct counted vmcnt ----------
// block = (b, rc): 32 rows. 4 waves = rowgroup(16) x colhalf(64).
// K = 1024 split into 4 chunks x 256 (8 MFMA k-steps of 32 each).
struct EPSmem {
  float buf[2][32][256];   // 64 KB, A tile dbuf; 1KB contiguous per row
  float qv[DATT];
  float wsc[DATT];
  float epart[2][32];
  float p_sm[32];
};

__global__ __launch_bounds__(256, 2) void epass_kernel(
    const float* __restrict__ enc,
    const __hip_bfloat16* __restrict__ WkT,
    const __hip_bfloat16* __restrict__ wlocT,
    const __hip_bfloat16* __restrict__ locf,
    const float* __restrict__ qvg,
    const float* __restrict__ wscore,
    float* __restrict__ energy_ws,
    float* __restrict__ mblk,
    float* __restrict__ sblk,
    float* __restrict__ ctxp) {
  __shared__ EPSmem sm;
  const int b = blockIdx.x >> 4, rc = blockIdx.x & 15;
  const int tid = threadIdx.x, lane = tid & 63, wv = tid >> 6;
  const int rg = wv >> 1, ch = wv & 1;
  const int lrow = lane & 15, lgrp = lane >> 4;
  const size_t growbase = (size_t)b * TT + rc * 32;

  // wave stages rows wv*8..+8; LDS 16B-chunk s holds global chunk s^(r&7)
  auto STAGE = [&](int p, int c) {
#pragma unroll
    for (int i = 0; i < 8; ++i) {
      const int r = wv * 8 + i;
      const float* src =
          enc + (growbase + r) * DENC + c * 256 + ((lane ^ (r & 7)) << 2);
      GLDS16(src, &sm.buf[p][r][0]);
    }
  };

  STAGE(0, 0);
  if (tid < DATT) sm.qv[tid] = qvg[(size_t)b * DATT + tid];
  else sm.wsc[tid - DATT] = wscore[tid - DATT];
  __syncthreads();   // qv/wsc visible; stage0 drained

  const __hip_bfloat16* pb =
      WkT + (size_t)(ch * 64 + lrow) * 1024 + lgrp * 8;

  bf16x8 bb[8][4];
  f32x4 acc[4];
#pragma unroll
  for (int n = 0; n < 4; ++n) acc[n] = (f32x4){0.f, 0.f, 0.f, 0.f};

#pragma unroll 1
  for (int c = 0; c < 4; ++c) {
    const int cur = c & 1;
    // (1) B for chunk c -> regs (K-range c*256..+256, within 1024)
#pragma unroll
    for (int s = 0; s < 8; ++s)
#pragma unroll
      for (int n = 0; n < 4; ++n)
        bb[s][n] = *reinterpret_cast<const bf16x8*>(
            pb + (size_t)n * 16384 + c * 256 + s * 32);
    // (2) prefetch chunk c+1 (stays in flight through compute of c)
    if (c < 3) STAGE(cur ^ 1, c + 1);
    __builtin_amdgcn_sched_barrier(0);
    // (3) drain B(c) + STAGE(c); keep STAGE(c+1) (8 newest) in flight
    if (c < 3) asm volatile("s_waitcnt vmcnt(8)" ::: "memory");
    else       asm volatile("s_waitcnt vmcnt(0)" ::: "memory");
    __builtin_amdgcn_sched_barrier(0);
    __builtin_amdgcn_s_barrier();          // tile c visible block-wide
    __builtin_amdgcn_sched_barrier(0);
    // (4) compute: 8 ksteps x 4 MFMA, pure LDS+regs
    const float* rowp = &sm.buf[cur][rg * 16 + lrow][0];
    const int x = lrow & 7;
#pragma unroll
    for (int s = 0; s < 8; ++s) {
      const int c0 = s * 8 + lgrp * 2;
      float4 f0 = *reinterpret_cast<const float4*>(rowp + ((c0 ^ x) << 2));
      float4 f1 = *reinterpret_cast<const float4*>(rowp + (((c0 + 1) ^ x) << 2));
      union { bf16x8 v; __hip_bfloat16 h[8]; } cv;
      cv.h[0] = __float2bfloat16(f0.x); cv.h[1] = __float2bfloat16(f0.y);
      cv.h[2] = __float2bfloat16(f0.z); cv.h[3] = __float2bfloat16(f0.w);
      cv.h[4] = __float2bfloat16(f1.x); cv.h[5] = __float2bfloat16(f1.y);
      cv.h[6] = __float2bfloat16(f1.z); cv.h[7] = __float2bfloat16(f1.w);
#pragma unroll
      for (int n = 0; n < 4; ++n)
        acc[n] = __builtin_amdgcn_mfma_f32_16x16x32_bf16(
            cv.v, bb[s][n], acc[n], 0, 0, 0);
    }
    __builtin_amdgcn_sched_barrier(0);
    __builtin_amdgcn_s_barrier();          // (5) safe to overwrite buf[cur]
    __builtin_amdgcn_sched_barrier(0);
  }

  // loc MFMA (K=32 location features; L2-hot)
  {
    bf16x8 alA = *reinterpret_cast<const bf16x8*>(
        locf + (growbase + rg * 16 + lrow) * NF + lgrp * 8);
#pragma unroll
    for (int n = 0; n < 4; ++n) {
      bf16x8 blB = *reinterpret_cast<const bf16x8*>(
          wlocT + (size_t)(ch * 64 + n * 16 + lrow) * NF + lgrp * 8);
      acc[n] = __builtin_amdgcn_mfma_f32_16x16x32_bf16(alA, blB, acc[n], 0, 0, 0);
    }
  }

  // epilogue: e[row] partial over this colhalf
#pragma unroll
  for (int r = 0; r < 4; ++r) {
    float e = 0.f;
#pragma unroll
    for (int n = 0; n < 4; ++n) {
      const int col = ch * 64 + n * 16 + lrow;
      float v = acc[n][r] + sm.qv[col];
      e = fmaf(fast_tanh(v), sm.wsc[col], e);
    }
    e += __shfl_xor(e, 1);
    e += __shfl_xor(e, 2);
    e += __shfl_xor(e, 4);
    e += __shfl_xor(e, 8);
    if (lrow == 0) sm.epart[ch][rg * 16 + lgrp * 4 + r] = e;
  }
  __syncthreads();

  // block flash partials over 32 rows (wave 0, lanes 0..31)
  if (wv == 0 && lane < 32) {
    float e = sm.epart[0][lane] + sm.epart[1][lane];
    energy_ws[(size_t)b * TT + rc * 32 + lane] = e;
    float mx = e;
#pragma unroll
    for (int off = 1; off < 32; off <<= 1) mx = fmaxf(mx, __shfl_xor(mx, off));
    float p = __expf(e - mx);
    sm.p_sm[lane] = p;
    float s = p;
#pragma unroll
    for (int off = 1; off < 32; off <<= 1) s += __shfl_xor(s, off);
    if (lane == 0) {
      mblk[blockIdx.x] = mx;
      sblk[blockIdx.x] = s;
    }
  }
  __syncthreads();

  // ctx partial: c[d] = sum_r p_r * enc[row, d]  (tile L2-hot)
  const float* base = enc + growbase * DENC + tid * 4;
  float4 a = {0.f, 0.f, 0.f, 0.f};
#pragma unroll 8
  for (int r = 0; r < 32; ++r) {
    float4 v = *reinterpret_cast<const float4*>(base + (size_t)r * DENC);
    const float wt = sm.p_sm[r];
    a.x = fmaf(wt, v.x, a.x);
    a.y = fmaf(wt, v.y, a.y);
    a.z = fmaf(wt, v.z, a.z);
    a.w = fmaf(wt, v.w, a.w);
  }
  *reinterpret_cast<float4*>(ctxp + (size_t)blockIdx.x * DENC + tid * 4) = a;
}

// ---------- finalize: combine 16 partials per b, emit w and ctx@Wv ----------
__global__ __launch_bounds__(512) void finalize_kernel(
    const float* __restrict__ energy_ws,
    const float* __restrict__ mblk,
    const float* __restrict__ sblk,
    const float* __restrict__ ctxp,
    const float* __restrict__ Wv,
    float* __restrict__ out_ctx,
    float* __restrict__ out_w) {
  __shared__ float sc[DENC];
  __shared__ float f16s[16];
  __shared__ float scal[2];
  const int b = blockIdx.x, tid = threadIdx.x;

  if (tid == 0) {
    float m = -INFINITY;
#pragma unroll
    for (int q = 0; q < 16; ++q) m = fmaxf(m, mblk[b * 16 + q]);
    float S = 0.f;
#pragma unroll
    for (int q = 0; q < 16; ++q) {
      float f = __expf(mblk[b * 16 + q] - m);
      f16s[q] = f;
      S = fmaf(sblk[b * 16 + q], f, S);
    }
    float invS = 1.f / S;
    scal[0] = m;
    scal[1] = invS;
#pragma unroll
    for (int q = 0; q < 16; ++q) f16s[q] *= invS;
  }
  __syncthreads();

  out_w[(size_t)b * TT + tid] =
      __expf(energy_ws[(size_t)b * TT + tid] - scal[0]) * scal[1];

#pragma unroll
  for (int h = 0; h < 2; ++h) {
    const int d = tid + h * 512;
    float s = 0.f;
#pragma unroll
    for (int q = 0; q < 16; ++q)
      s += ctxp[((size_t)(b * 16 + q)) * DENC + d] * f16s[q];
    sc[d] = s;
  }
  __syncthreads();

  float acc = 0.f;
#pragma unroll 8
  for (int dd = 0; dd < DENC; ++dd)
    acc = fmaf(sc[dd], Wv[(size_t)dd * DDEC + tid], acc);
  out_ctx[(size_t)b * DDEC + tid] = acc;
}

extern "C" void kernel_launch(void* const* d_in, const int* in_sizes, int n_in,
                              void* d_out, int out_size, void* d_ws, size_t ws_size,
                              hipStream_t stream) {
  const float* query  = (const float*)d_in[0];
  const float* enc    = (const float*)d_in[1];
  const float* attw   = (const float*)d_in[2];
  const float* Wq     = (const float*)d_in[3];
  const float* Wk     = (const float*)d_in[4];
  const float* Wv     = (const float*)d_in[5];
  const float* Wloc   = (const float*)d_in[6];
  const float* convw  = (const float*)d_in[7];
  const float* convb  = (const float*)d_in[8];
  const float* wscore = (const float*)d_in[9];

  float* ctx  = (float*)d_out;               // [256][512]
  float* neww = (float*)d_out + NB * TT;     // [256][512]

  char* ws = (char*)d_ws;
  float* ctxp            = (float*)ws;                        // 4096*1024*4 = 16 MB
  __hip_bfloat16* WkT    = (__hip_bfloat16*)(ws + 16777216);  // 256 KB
  float* qvg             = (float*)(ws + 17039360);           // 128 KB
  float* energy_ws       = (float*)(ws + 17170432);           // 512 KB
  __hip_bfloat16* wlocT  = (__hip_bfloat16*)(ws + 17694720);  // 8 KB
  __hip_bfloat16* locf   = (__hip_bfloat16*)(ws + 17702912);  // 8 MB
  float* mblk            = (float*)(ws + 26091520);           // 16 KB
  float* sblk            = (float*)(ws + 26107904);           // 16 KB

  hipLaunchKernelGGL(prep_wkt, dim3(256), dim3(256), 0, stream, Wk, WkT);
  hipLaunchKernelGGL(prep_wloc, dim3(16), dim3(256), 0, stream, Wloc, wlocT);
  hipLaunchKernelGGL(prep_qv, dim3(NB), dim3(128), 0, stream, query, Wq, qvg);
  hipLaunchKernelGGL(prep_locf, dim3(NB), dim3(512), 0, stream,
                     attw, convw, convb, locf);
  hipLaunchKernelGGL(epass_kernel, dim3(NB * 16), dim3(256), 0, stream,
                     enc, WkT, wlocT, locf, qvg, wscore,
                     energy_ws, mblk, sblk, ctxp);
  hipLaunchKernelGGL(finalize_kernel, dim3(NB), dim3(512), 0, stream,
                     energy_ws, mblk, sblk, ctxp, Wv, ctx, neww);
}